// Round 9
// baseline (315.454 us; speedup 1.0000x reference)
//
#include <hip/hip_runtime.h>
#include <hip/hip_bf16.h>

#define B_ 2
#define S_ 2048
#define D_ 1024
#define H_ 16
#define AD_ 64

typedef __attribute__((ext_vector_type(8))) short bf16x8;
typedef __attribute__((ext_vector_type(4))) float f32x4;

__device__ inline unsigned short f2bf(float f) {
  __hip_bfloat16 h = __float2bfloat16(f);
  return *reinterpret_cast<unsigned short*>(&h);
}

__device__ inline void gload16(const void* g, void* lds) {
  __builtin_amdgcn_global_load_lds((const __attribute__((address_space(1))) void*)g,
                                   (__attribute__((address_space(3))) void*)lds,
                                   16, 0, 0);
}

#define WAITV(N) asm volatile("s_waitcnt vmcnt(" #N ")" ::: "memory")
#define WAITL()  asm volatile("s_waitcnt lgkmcnt(0)" ::: "memory")
#define BAR()    __builtin_amdgcn_s_barrier()
#define SCHED0() __builtin_amdgcn_sched_barrier(0)

// ---------------------------------------------------------------------------
// Cast q,k,v (f32) -> bf16, 8 elems/thread. 3 x 2^19 chunks exactly.
// ---------------------------------------------------------------------------
__global__ __launch_bounds__(256) void castbf3(
    const float* __restrict__ q, const float* __restrict__ k,
    const float* __restrict__ v, __hip_bfloat16* __restrict__ Qb,
    __hip_bfloat16* __restrict__ Kb, __hip_bfloat16* __restrict__ Vb) {
  const int t = blockIdx.x * 256 + threadIdx.x;
  const int src = t >> 19;
  const int off = t & ((1 << 19) - 1);
  const float* in = src == 0 ? q : (src == 1 ? k : v);
  __hip_bfloat16* out = src == 0 ? Qb : (src == 1 ? Kb : Vb);
  float4 a = ((const float4*)in)[off * 2];
  float4 b = ((const float4*)in)[off * 2 + 1];
  bf16x8 o;
  o[0] = (short)f2bf(a.x); o[1] = (short)f2bf(a.y);
  o[2] = (short)f2bf(a.z); o[3] = (short)f2bf(a.w);
  o[4] = (short)f2bf(b.x); o[5] = (short)f2bf(b.y);
  o[6] = (short)f2bf(b.z); o[7] = (short)f2bf(b.w);
  ((bf16x8*)out)[off] = o;
}

// ---------------------------------------------------------------------------
// Transpose + cast all four W (1024x1024 f32 [k][n]) -> Wt bf16 [n][k].
// ---------------------------------------------------------------------------
__global__ __launch_bounds__(256) void wtrans4(
    const float* __restrict__ W0, const float* __restrict__ W1,
    const float* __restrict__ W2, const float* __restrict__ W3,
    __hip_bfloat16* __restrict__ T0, __hip_bfloat16* __restrict__ T1,
    __hip_bfloat16* __restrict__ T2, __hip_bfloat16* __restrict__ T3) {
  const int z = blockIdx.z;
  const float* W = z == 0 ? W0 : z == 1 ? W1 : z == 2 ? W2 : W3;
  __hip_bfloat16* Wt = z == 0 ? T0 : z == 1 ? T1 : z == 2 ? T2 : T3;
  __shared__ alignas(16) unsigned short T[64][72];
  const int tx = threadIdx.x;
  const int n0 = blockIdx.x * 64, k0 = blockIdx.y * 64;
#pragma unroll
  for (int i = 0; i < 4; ++i) {
    int kl = (tx >> 4) + i * 16;
    int nl = (tx & 15) * 4;
    float4 val = *(const float4*)(W + (size_t)(k0 + kl) * 1024 + n0 + nl);
    T[kl][nl + 0] = f2bf(val.x);
    T[kl][nl + 1] = f2bf(val.y);
    T[kl][nl + 2] = f2bf(val.z);
    T[kl][nl + 3] = f2bf(val.w);
  }
  __syncthreads();
#pragma unroll
  for (int i = 0; i < 4; ++i) {
    int nl = (tx >> 4) + i * 16;
    int kl = (tx & 15) * 4;
    ushort4 o;
    o.x = T[kl + 0][nl];
    o.y = T[kl + 1][nl];
    o.z = T[kl + 2][nl];
    o.w = T[kl + 3][nl];
    *(ushort4*)(Wt + (size_t)(n0 + nl) * 1024 + k0 + kl) = o;
  }
}

// ---------------------------------------------------------------------------
// Merged QKV GEMM, bf16 A (pre-cast), pure global_load_lds staging,
// DEPTH-2 prefetch ring (3 bufs) with counted-vmcnt publish (T3/T4).
// ---------------------------------------------------------------------------
__global__ __launch_bounds__(256) void qkv_gemm(
    const __hip_bfloat16* __restrict__ Qb, const __hip_bfloat16* __restrict__ Kb,
    const __hip_bfloat16* __restrict__ Vb, const __hip_bfloat16* __restrict__ WtQ,
    const __hip_bfloat16* __restrict__ WtK, const __hip_bfloat16* __restrict__ WtV,
    __hip_bfloat16* __restrict__ Qh, __hip_bfloat16* __restrict__ Kh,
    __hip_bfloat16* __restrict__ Vt) {
  __shared__ alignas(16) __hip_bfloat16 As[3][128 * 32];
  __shared__ alignas(16) __hip_bfloat16 Bs[3][128 * 32];
  const int bid = blockIdx.x;
  const int xcd = bid & 7, li = bid >> 3;
  const int bmi = xcd * 4 + li / 24, ny = li % 24;
  const int mat = ny >> 3, bni = ny & 7;
  const __hip_bfloat16* A = mat == 0 ? Qb : (mat == 1 ? Kb : Vb);
  const __hip_bfloat16* Bt = mat == 0 ? WtQ : (mat == 1 ? WtK : WtV);
  const int bm = bmi * 128, bn = bni * 128;

  const int tid = threadIdx.x;
  const int wave = tid >> 6, lane = tid & 63;
  const int g = lane >> 4, c = lane & 15;
  const int wr = (wave >> 1) * 64, wc = (wave & 1) * 64;
  f32x4 acc[4][4] = {};

  const int ch0 = wave * 64 + lane, ch1 = 256 + wave * 64 + lane;
  const int am0 = ch0 >> 2, ak0 = ch0 & 3, am1 = ch1 >> 2, ak1 = ch1 & 3;
  const size_t asrc0 = (size_t)(bm + am0) * D_ + (ak0 ^ ((am0 ^ (am0 >> 2)) & 3)) * 8;
  const size_t asrc1 = (size_t)(bm + am1) * D_ + (ak1 ^ ((am1 ^ (am1 >> 2)) & 3)) * 8;
  const size_t bsrc0 = (size_t)(bn + am0) * D_ + (ak0 ^ ((am0 ^ (am0 >> 2)) & 3)) * 8;
  const size_t bsrc1 = (size_t)(bn + am1) * D_ + (ak1 ^ ((am1 ^ (am1 >> 2)) & 3)) * 8;
  const int dst0 = (wave * 64) * 16, dst1 = (256 + wave * 64) * 16;

#define STG(kofs, bi)                                     \
  do {                                                    \
    gload16(A + asrc0 + (kofs), (char*)As[bi] + dst0);    \
    gload16(A + asrc1 + (kofs), (char*)As[bi] + dst1);    \
    gload16(Bt + bsrc0 + (kofs), (char*)Bs[bi] + dst0);   \
    gload16(Bt + bsrc1 + (kofs), (char*)Bs[bi] + dst1);   \
  } while (0)

  STG(0, 0);
  STG(32, 1);
  int cur = 0;
  for (int s = 0; s < 32; ++s) {
    WAITL();
    WAITV(4);
    BAR();
    SCHED0();
    if (s + 2 < 32) {
      int stg = cur == 0 ? 2 : cur - 1;
      STG((size_t)(s + 2) * 32, stg);
    }
    bf16x8 a[4], b[4];
#pragma unroll
    for (int mi = 0; mi < 4; ++mi) {
      int row = wr + mi * 16 + c;
      a[mi] = *(const bf16x8*)((const char*)As[cur] + row * 64 +
                               ((g ^ ((row ^ (row >> 2)) & 3)) << 4));
    }
#pragma unroll
    for (int ni = 0; ni < 4; ++ni) {
      int row = wc + ni * 16 + c;
      b[ni] = *(const bf16x8*)((const char*)Bs[cur] + row * 64 +
                               ((g ^ ((row ^ (row >> 2)) & 3)) << 4));
    }
#pragma unroll
    for (int mi = 0; mi < 4; ++mi)
#pragma unroll
      for (int ni = 0; ni < 4; ++ni)
        acc[mi][ni] =
            __builtin_amdgcn_mfma_f32_16x16x32_bf16(a[mi], b[ni], acc[mi][ni], 0, 0, 0);
    cur = cur == 2 ? 0 : cur + 1;
  }
#undef STG

  __hip_bfloat16* Chead = mat == 0 ? Qh : Kh;
#pragma unroll
  for (int mi = 0; mi < 4; ++mi) {
#pragma unroll
    for (int ni = 0; ni < 4; ++ni) {
#pragma unroll
      for (int r = 0; r < 4; ++r) {
        int grow = bm + wr + mi * 16 + g * 4 + r;
        int gcol = bn + wc + ni * 16 + c;
        float val = acc[mi][ni][r];
        int bb = grow >> 11, s = grow & 2047;
        int h = gcol >> 6, ad = gcol & 63;
        if (mat < 2)
          Chead[(((size_t)(bb * H_ + h)) * S_ + s) * AD_ + ad] = __float2bfloat16(val);
        else
          Vt[(((size_t)(bb * H_ + h)) * AD_ + ad) * S_ + s] = __float2bfloat16(val);
      }
    }
  }
}

// ---------------------------------------------------------------------------
// Fallback QKV (f32 A, VALU cast) — used if ws too small.
// ---------------------------------------------------------------------------
__global__ __launch_bounds__(256) void qkv_gemm_f32(
    const float* __restrict__ qp, const float* __restrict__ kp,
    const float* __restrict__ vp, const __hip_bfloat16* __restrict__ WtQ,
    const __hip_bfloat16* __restrict__ WtK, const __hip_bfloat16* __restrict__ WtV,
    __hip_bfloat16* __restrict__ Qh, __hip_bfloat16* __restrict__ Kh,
    __hip_bfloat16* __restrict__ Vt) {
  __shared__ alignas(16) __hip_bfloat16 As[128 * 32];
  __shared__ alignas(16) __hip_bfloat16 Bs[128 * 32];
  const int bid = blockIdx.x;
  const int xcd = bid & 7, li = bid >> 3;
  const int bmi = xcd * 4 + li / 24, ny = li % 24;
  const int mat = ny >> 3, bni = ny & 7;
  const float* A = mat == 0 ? qp : (mat == 1 ? kp : vp);
  const __hip_bfloat16* Bt = mat == 0 ? WtQ : (mat == 1 ? WtK : WtV);
  const int bm = bmi * 128, bn = bni * 128;
  const int tid = threadIdx.x;
  const int wave = tid >> 6, lane = tid & 63;
  const int g = lane >> 4, c = lane & 15;
  const int wr = (wave >> 1) * 64, wc = (wave & 1) * 64;
  f32x4 acc[4][4] = {};
  for (int k0 = 0; k0 < D_; k0 += 32) {
#pragma unroll
    for (int i = 0; i < 4; ++i) {
      int chunk = i * 256 + tid;
      int m = chunk >> 3, kc = chunk & 7;
      float4 v4 = *(const float4*)(A + (size_t)(bm + m) * D_ + k0 + kc * 4);
      ushort4 b;
      b.x = f2bf(v4.x); b.y = f2bf(v4.y); b.z = f2bf(v4.z); b.w = f2bf(v4.w);
      int sw = (kc >> 1) ^ ((m ^ (m >> 2)) & 3);
      *(ushort4*)((char*)As + m * 64 + (sw << 4) + ((kc & 1) << 3)) = b;
    }
#pragma unroll
    for (int i = 0; i < 2; ++i) {
      int cb = i * 256 + wave * 64;
      int chunk = cb + lane;
      int n = chunk >> 2, kc = chunk & 3;
      int sw = kc ^ ((n ^ (n >> 2)) & 3);
      gload16(Bt + (size_t)(bn + n) * D_ + k0 + sw * 8, (char*)Bs + cb * 16);
    }
    __syncthreads();
    bf16x8 a[4], b[4];
#pragma unroll
    for (int mi = 0; mi < 4; ++mi) {
      int row = wr + mi * 16 + c;
      a[mi] = *(const bf16x8*)((const char*)As + row * 64 +
                               ((g ^ ((row ^ (row >> 2)) & 3)) << 4));
    }
#pragma unroll
    for (int ni = 0; ni < 4; ++ni) {
      int row = wc + ni * 16 + c;
      b[ni] = *(const bf16x8*)((const char*)Bs + row * 64 +
                               ((g ^ ((row ^ (row >> 2)) & 3)) << 4));
    }
#pragma unroll
    for (int mi = 0; mi < 4; ++mi)
#pragma unroll
      for (int ni = 0; ni < 4; ++ni)
        acc[mi][ni] =
            __builtin_amdgcn_mfma_f32_16x16x32_bf16(a[mi], b[ni], acc[mi][ni], 0, 0, 0);
    __syncthreads();
  }
  __hip_bfloat16* Chead = mat == 0 ? Qh : Kh;
#pragma unroll
  for (int mi = 0; mi < 4; ++mi)
#pragma unroll
    for (int ni = 0; ni < 4; ++ni)
#pragma unroll
      for (int r = 0; r < 4; ++r) {
        int grow = bm + wr + mi * 16 + g * 4 + r;
        int gcol = bn + wc + ni * 16 + c;
        float val = acc[mi][ni][r];
        int bb = grow >> 11, s = grow & 2047;
        int h = gcol >> 6, ad = gcol & 63;
        if (mat < 2)
          Chead[(((size_t)(bb * H_ + h)) * S_ + s) * AD_ + ad] = __float2bfloat16(val);
        else
          Vt[(((size_t)(bb * H_ + h)) * AD_ + ad) * S_ + s] = __float2bfloat16(val);
      }
}

// ---------------------------------------------------------------------------
// O-projection GEMM, 128x64 tiles -> 512 blocks (2/CU), XCD-chunked.
// ---------------------------------------------------------------------------
__global__ __launch_bounds__(256) void ogemm(const __hip_bfloat16* __restrict__ A,
                                             const __hip_bfloat16* __restrict__ Bt,
                                             float* __restrict__ Cp) {
  __shared__ alignas(16) __hip_bfloat16 As[128 * 32];
  __shared__ alignas(16) __hip_bfloat16 Bs[64 * 32];
  const int bid = blockIdx.x;
  const int xcd = bid & 7, li = bid >> 3;
  const int bmi = xcd * 4 + (li >> 4), bni = li & 15;
  const int bm = bmi * 128, bn = bni * 64;
  const int tid = threadIdx.x;
  const int wave = tid >> 6, lane = tid & 63;
  const int g = lane >> 4, c = lane & 15;
  const int wr = (wave >> 1) * 64, wc = (wave & 1) * 32;
  f32x4 acc[4][2] = {};

  for (int k0 = 0; k0 < D_; k0 += 32) {
#pragma unroll
    for (int i = 0; i < 2; ++i) {
      int cb = i * 256 + wave * 64;
      int chunk = cb + lane;
      int m = chunk >> 2, kc = chunk & 3;
      int sw = kc ^ ((m ^ (m >> 2)) & 3);
      gload16(A + (size_t)(bm + m) * D_ + k0 + sw * 8, (char*)As + cb * 16);
    }
    {
      int cb = wave * 64;
      int chunk = cb + lane;
      int n = chunk >> 2, kc = chunk & 3;
      int sw = kc ^ ((n ^ (n >> 2)) & 3);
      gload16(Bt + (size_t)(bn + n) * D_ + k0 + sw * 8, (char*)Bs + cb * 16);
    }
    __syncthreads();

    bf16x8 a[4], b[2];
#pragma unroll
    for (int mi = 0; mi < 4; ++mi) {
      int row = wr + mi * 16 + c;
      a[mi] = *(const bf16x8*)((const char*)As + row * 64 +
                               ((g ^ ((row ^ (row >> 2)) & 3)) << 4));
    }
#pragma unroll
    for (int ni = 0; ni < 2; ++ni) {
      int row = wc + ni * 16 + c;
      b[ni] = *(const bf16x8*)((const char*)Bs + row * 64 +
                               ((g ^ ((row ^ (row >> 2)) & 3)) << 4));
    }
#pragma unroll
    for (int mi = 0; mi < 4; ++mi)
#pragma unroll
      for (int ni = 0; ni < 2; ++ni)
        acc[mi][ni] =
            __builtin_amdgcn_mfma_f32_16x16x32_bf16(a[mi], b[ni], acc[mi][ni], 0, 0, 0);
    __syncthreads();
  }

#pragma unroll
  for (int mi = 0; mi < 4; ++mi)
#pragma unroll
    for (int ni = 0; ni < 2; ++ni)
#pragma unroll
      for (int r = 0; r < 4; ++r) {
        int grow = bm + wr + mi * 16 + g * 4 + r;
        int gcol = bn + wc + ni * 16 + c;
        Cp[(size_t)grow * 1024 + gcol] = acc[mi][ni][r];
      }
}

// ---------------------------------------------------------------------------
// Fused attention v7 = v5 structure (KVBLK=64, 48 KB LDS, 24 waves/CU —
// verified 282.9 µs config) + PASS REBALANCE ONLY:
//   pass 1: stage K+V, QK^T + exp + rowsum + P-pack + UNNORMALIZED PV;
//           ctx written after reduce (shfl-invZ transpose, verified R7).
//   pass 2: LEAN — stage K only, QK^T, exp*invZ, NONTEMPORAL f32x4 stores.
//           WAITV(4): own 2 K loads drained, 4 prev stores float across BAR.
// ---------------------------------------------------------------------------
__global__ __launch_bounds__(512) void attn_fused(const __hip_bfloat16* __restrict__ Qh,
                                                  const __hip_bfloat16* __restrict__ Kh,
                                                  const __hip_bfloat16* __restrict__ Vt,
                                                  float* __restrict__ attn,
                                                  __hip_bfloat16* __restrict__ ctx) {
  __shared__ alignas(16) __hip_bfloat16 Kbuf[2][64 * 64];
  __shared__ alignas(16) __hip_bfloat16 Vbuf[2][64 * 64];
  __shared__ alignas(16) __hip_bfloat16 Ps[8][16 * 64];
  const int tid = threadIdx.x;
  const int wave = tid >> 6, lane = tid & 63;
  const int g = lane >> 4, c = lane & 15;
  const int bid = blockIdx.x;
  const int xcd = bid & 7, li = bid >> 3;
  const int bh = xcd * 4 + (li >> 4), qt = li & 15;
  const int qrow0 = qt * 128 + wave * 16;

  const __hip_bfloat16* Kbh = Kh + (size_t)bh * S_ * AD_;
  const __hip_bfloat16* Vbh = Vt + (size_t)bh * AD_ * S_;

  const __hip_bfloat16* Qbase = Qh + ((size_t)bh * S_ + qrow0 + c) * AD_;
  bf16x8 qa0 = *(const bf16x8*)(Qbase + g * 8);
  bf16x8 qa1 = *(const bf16x8*)(Qbase + 32 + g * 8);

  // staging: 512 chunks of 16B per 64x64 tile, 512 threads -> 1 chunk each
  const int ch = wave * 64 + lane;
  const int r0 = ch >> 3, q0 = ch & 7;
  const int ksrc = r0 * AD_ + ((q0 ^ (r0 & 7)) * 8);            // K: [key][ad]
  const size_t vsrc = (size_t)r0 * S_ + ((q0 ^ (r0 & 7)) * 8);  // V: [ad][s]
  const int dstu = wave * 1024;  // wave-uniform; HW adds lane*16

#define STAGE_K(kt, bufp) \
  gload16(Kbh + (size_t)(kt) * 64 * AD_ + ksrc, (char*)(bufp) + dstu)
#define STAGE_V(kt, bufp) \
  gload16(Vbh + (size_t)(kt) * 64 + vsrc, (char*)(bufp) + dstu)

  const int csw = c & 7;
  char* Pw = (char*)Ps[wave] + c * 128;

  // ---- pass 1: rowsum + unnormalized PV ----
  f32x4 ctxacc[4] = {};
  float rowsum = 0.f;
  STAGE_K(0, Kbuf[0]);
  STAGE_V(0, Vbuf[0]);
  for (int kt = 0; kt < 32; ++kt) {
    const int cur = kt & 1;
    WAITL();
    WAITV(0);  // publish own 2 staging loads of tile kt (no stores in flight)
    BAR();
    SCHED0();
    if (kt < 31) {
      STAGE_K(kt + 1, Kbuf[cur ^ 1]);
      STAGE_V(kt + 1, Vbuf[cur ^ 1]);
    }
    const char* Kc = (const char*)Kbuf[cur];
    const char* Vc = (const char*)Vbuf[cur];
#pragma unroll
    for (int t = 0; t < 4; ++t) {
      const char* kb = Kc + (t * 16 + c) * 128;
      bf16x8 k0 = *(const bf16x8*)(kb + ((g ^ csw) << 4));
      bf16x8 k1 = *(const bf16x8*)(kb + (((4 + g) ^ csw) << 4));
      f32x4 s = {0.f, 0.f, 0.f, 0.f};
      s = __builtin_amdgcn_mfma_f32_16x16x32_bf16(k0, qa0, s, 0, 0, 0);
      s = __builtin_amdgcn_mfma_f32_16x16x32_bf16(k1, qa1, s, 0, 0, 0);
      f32x4 p;
#pragma unroll
      for (int r = 0; r < 4; ++r) p[r] = __expf(s[r] * 0.125f);
      rowsum += p[0] + p[1] + p[2] + p[3];
      ushort4 pk;
      pk.x = f2bf(p[0]); pk.y = f2bf(p[1]); pk.z = f2bf(p[2]); pk.w = f2bf(p[3]);
      *(ushort4*)(Pw + (((2 * t + (g >> 1)) ^ csw) << 4) + ((g & 1) << 3)) = pk;
    }
    // PV with unnormalized P
#pragma unroll
    for (int h2 = 0; h2 < 2; ++h2) {
      bf16x8 pa = *(const bf16x8*)(Pw + ((((h2 << 2) + g) ^ csw) << 4));
#pragma unroll
      for (int ni = 0; ni < 4; ++ni) {
        const char* vrow = Vc + (ni * 16 + c) * 128;
        bf16x8 vb = *(const bf16x8*)(vrow + (((h2 * 4 + g) ^ csw) << 4));
        ctxacc[ni] = __builtin_amdgcn_mfma_f32_16x16x32_bf16(pa, vb, ctxacc[ni], 0, 0, 0);
      }
    }
  }
  rowsum += __shfl_xor(rowsum, 16);
  rowsum += __shfl_xor(rowsum, 32);
  const float invZ = 1.0f / rowsum;

  // ctx write now: ctxacc rows are qrow g*4+r -> transpose invZ via shfl
  float invZr[4];
#pragma unroll
  for (int r = 0; r < 4; ++r) invZr[r] = __shfl(invZ, g * 4 + r);
  {
    const int b = bh >> 4, h = bh & 15;
#pragma unroll
    for (int ni = 0; ni < 4; ++ni)
#pragma unroll
      for (int r = 0; r < 4; ++r) {
        int qg = qrow0 + g * 4 + r;
        int col = h * 64 + ni * 16 + c;
        ctx[((size_t)b * S_ + qg) * 1024 + col] =
            __float2bfloat16(ctxacc[ni][r] * invZr[r]);
      }
  }

  // ---- pass 2: lean attn store pass ----
  float* attn_row = attn + ((size_t)bh * S_ + qrow0 + c) * S_;
  STAGE_K(0, Kbuf[0]);
  WAITV(0);  // drains ctx stores + own tile-0 K load (one-time)
  for (int kt = 0; kt < 32; ++kt) {
    const int cur = kt & 1;
    WAITL();
    WAITV(4);  // own K load of kt drained; 4 prev nt-stores float on
    BAR();
    SCHED0();
    if (kt < 31) STAGE_K(kt + 1, Kbuf[cur ^ 1]);
    const char* Kc = (const char*)Kbuf[cur];
#pragma unroll
    for (int t = 0; t < 4; ++t) {
      const char* kb = Kc + (t * 16 + c) * 128;
      bf16x8 k0 = *(const bf16x8*)(kb + ((g ^ csw) << 4));
      bf16x8 k1 = *(const bf16x8*)(kb + (((4 + g) ^ csw) << 4));
      f32x4 s = {0.f, 0.f, 0.f, 0.f};
      s = __builtin_amdgcn_mfma_f32_16x16x32_bf16(k0, qa0, s, 0, 0, 0);
      s = __builtin_amdgcn_mfma_f32_16x16x32_bf16(k1, qa1, s, 0, 0, 0);
      f32x4 p;
#pragma unroll
      for (int r = 0; r < 4; ++r) p[r] = __expf(s[r] * 0.125f) * invZ;
      __builtin_nontemporal_store(p, (f32x4*)(attn_row + kt * 64 + t * 16 + g * 4));
    }
  }
#undef STAGE_K
#undef STAGE_V
}

// ---------------------------------------------------------------------------
extern "C" void kernel_launch(void* const* d_in, const int* in_sizes, int n_in,
                              void* d_out, int out_size, void* d_ws, size_t ws_size,
                              hipStream_t stream) {
  const float* q = (const float*)d_in[0];
  const float* k = (const float*)d_in[1];
  const float* v = (const float*)d_in[2];
  const float* WQ = (const float*)d_in[3];
  const float* WK = (const float*)d_in[4];
  const float* WV = (const float*)d_in[5];
  const float* WO = (const float*)d_in[6];

  float* out_x = (float*)d_out;                      // (B,S,1024) f32
  float* out_attn = out_x + (size_t)B_ * S_ * 1024;  // (B,H,S,S)  f32

  const size_t W1 = 1048576;  // elems per Wt
  const size_t T4 = 4194304;  // elems per (B,S,D) bf16 tensor
  __hip_bfloat16* base = (__hip_bfloat16*)d_ws;
  __hip_bfloat16* WtQ = base;
  __hip_bfloat16* WtK = WtQ + W1;
  __hip_bfloat16* WtV = WtK + W1;
  __hip_bfloat16* WtO = WtV + W1;
  __hip_bfloat16* Qh = WtO + W1;
  __hip_bfloat16* Kh = Qh + T4;
  __hip_bfloat16* Vt = Kh + T4;

  wtrans4<<<dim3(16, 16, 4), 256, 0, stream>>>(WQ, WK, WV, WO, WtQ, WtK, WtV, WtO);

  if (ws_size >= (4 * W1 + 6 * T4) * sizeof(__hip_bfloat16)) {
    __hip_bfloat16* Qb = Vt + T4;
    __hip_bfloat16* Kb = Qb + T4;
    __hip_bfloat16* Vb = Kb + T4;
    __hip_bfloat16* ctx = Qb;  // Qb dead after qkv_gemm; reuse for ctx
    castbf3<<<6144, 256, 0, stream>>>(q, k, v, Qb, Kb, Vb);
    qkv_gemm<<<768, 256, 0, stream>>>(Qb, Kb, Vb, WtQ, WtK, WtV, Qh, Kh, Vt);
    attn_fused<<<512, 512, 0, stream>>>(Qh, Kh, Vt, out_attn, ctx);
    ogemm<<<512, 256, 0, stream>>>(ctx, WtO, out_x);
  } else {
    __hip_bfloat16* ctx = Vt + T4;
    qkv_gemm_f32<<<768, 256, 0, stream>>>(q, k, v, WtQ, WtK, WtV, Qh, Kh, Vt);
    attn_fused<<<512, 512, 0, stream>>>(Qh, Kh, Vt, out_attn, ctx);
    ogemm<<<512, 256, 0, stream>>>(ctx, WtO, out_x);
  }
}

// Round 11
// 280.812 us; speedup vs baseline: 1.1234x; 1.1234x over previous
//
#include <hip/hip_runtime.h>
#include <hip/hip_bf16.h>

#define B_ 2
#define S_ 2048
#define D_ 1024
#define H_ 16
#define AD_ 64

typedef __attribute__((ext_vector_type(8))) short bf16x8;
typedef __attribute__((ext_vector_type(4))) float f32x4;

__device__ inline unsigned short f2bf(float f) {
  __hip_bfloat16 h = __float2bfloat16(f);
  return *reinterpret_cast<unsigned short*>(&h);
}

__device__ inline void gload16(const void* g, void* lds) {
  __builtin_amdgcn_global_load_lds((const __attribute__((address_space(1))) void*)g,
                                   (__attribute__((address_space(3))) void*)lds,
                                   16, 0, 0);
}

#define WAITV(N) asm volatile("s_waitcnt vmcnt(" #N ")" ::: "memory")
#define WAITL()  asm volatile("s_waitcnt lgkmcnt(0)" ::: "memory")
#define BAR()    __builtin_amdgcn_s_barrier()
#define SCHED0() __builtin_amdgcn_sched_barrier(0)

// ---------------------------------------------------------------------------
// Cast q,k,v (f32) -> bf16, 8 elems/thread. 3 x 2^19 chunks exactly.
// ---------------------------------------------------------------------------
__global__ __launch_bounds__(256) void castbf3(
    const float* __restrict__ q, const float* __restrict__ k,
    const float* __restrict__ v, __hip_bfloat16* __restrict__ Qb,
    __hip_bfloat16* __restrict__ Kb, __hip_bfloat16* __restrict__ Vb) {
  const int t = blockIdx.x * 256 + threadIdx.x;
  const int src = t >> 19;
  const int off = t & ((1 << 19) - 1);
  const float* in = src == 0 ? q : (src == 1 ? k : v);
  __hip_bfloat16* out = src == 0 ? Qb : (src == 1 ? Kb : Vb);
  float4 a = ((const float4*)in)[off * 2];
  float4 b = ((const float4*)in)[off * 2 + 1];
  bf16x8 o;
  o[0] = (short)f2bf(a.x); o[1] = (short)f2bf(a.y);
  o[2] = (short)f2bf(a.z); o[3] = (short)f2bf(a.w);
  o[4] = (short)f2bf(b.x); o[5] = (short)f2bf(b.y);
  o[6] = (short)f2bf(b.z); o[7] = (short)f2bf(b.w);
  ((bf16x8*)out)[off] = o;
}

// ---------------------------------------------------------------------------
// Transpose + cast all four W (1024x1024 f32 [k][n]) -> Wt bf16 [n][k].
// ---------------------------------------------------------------------------
__global__ __launch_bounds__(256) void wtrans4(
    const float* __restrict__ W0, const float* __restrict__ W1,
    const float* __restrict__ W2, const float* __restrict__ W3,
    __hip_bfloat16* __restrict__ T0, __hip_bfloat16* __restrict__ T1,
    __hip_bfloat16* __restrict__ T2, __hip_bfloat16* __restrict__ T3) {
  const int z = blockIdx.z;
  const float* W = z == 0 ? W0 : z == 1 ? W1 : z == 2 ? W2 : W3;
  __hip_bfloat16* Wt = z == 0 ? T0 : z == 1 ? T1 : z == 2 ? T2 : T3;
  __shared__ alignas(16) unsigned short T[64][72];
  const int tx = threadIdx.x;
  const int n0 = blockIdx.x * 64, k0 = blockIdx.y * 64;
#pragma unroll
  for (int i = 0; i < 4; ++i) {
    int kl = (tx >> 4) + i * 16;
    int nl = (tx & 15) * 4;
    float4 val = *(const float4*)(W + (size_t)(k0 + kl) * 1024 + n0 + nl);
    T[kl][nl + 0] = f2bf(val.x);
    T[kl][nl + 1] = f2bf(val.y);
    T[kl][nl + 2] = f2bf(val.z);
    T[kl][nl + 3] = f2bf(val.w);
  }
  __syncthreads();
#pragma unroll
  for (int i = 0; i < 4; ++i) {
    int nl = (tx >> 4) + i * 16;
    int kl = (tx & 15) * 4;
    ushort4 o;
    o.x = T[kl + 0][nl];
    o.y = T[kl + 1][nl];
    o.z = T[kl + 2][nl];
    o.w = T[kl + 3][nl];
    *(ushort4*)(Wt + (size_t)(n0 + nl) * 1024 + k0 + kl) = o;
  }
}

// ---------------------------------------------------------------------------
// Merged QKV GEMM, bf16 A (pre-cast), pure global_load_lds staging,
// DEPTH-2 prefetch ring (3 bufs) with counted-vmcnt publish (T3/T4).
// ---------------------------------------------------------------------------
__global__ __launch_bounds__(256) void qkv_gemm(
    const __hip_bfloat16* __restrict__ Qb, const __hip_bfloat16* __restrict__ Kb,
    const __hip_bfloat16* __restrict__ Vb, const __hip_bfloat16* __restrict__ WtQ,
    const __hip_bfloat16* __restrict__ WtK, const __hip_bfloat16* __restrict__ WtV,
    __hip_bfloat16* __restrict__ Qh, __hip_bfloat16* __restrict__ Kh,
    __hip_bfloat16* __restrict__ Vt) {
  __shared__ alignas(16) __hip_bfloat16 As[3][128 * 32];
  __shared__ alignas(16) __hip_bfloat16 Bs[3][128 * 32];
  const int bid = blockIdx.x;
  const int xcd = bid & 7, li = bid >> 3;
  const int bmi = xcd * 4 + li / 24, ny = li % 24;
  const int mat = ny >> 3, bni = ny & 7;
  const __hip_bfloat16* A = mat == 0 ? Qb : (mat == 1 ? Kb : Vb);
  const __hip_bfloat16* Bt = mat == 0 ? WtQ : (mat == 1 ? WtK : WtV);
  const int bm = bmi * 128, bn = bni * 128;

  const int tid = threadIdx.x;
  const int wave = tid >> 6, lane = tid & 63;
  const int g = lane >> 4, c = lane & 15;
  const int wr = (wave >> 1) * 64, wc = (wave & 1) * 64;
  f32x4 acc[4][4] = {};

  const int ch0 = wave * 64 + lane, ch1 = 256 + wave * 64 + lane;
  const int am0 = ch0 >> 2, ak0 = ch0 & 3, am1 = ch1 >> 2, ak1 = ch1 & 3;
  const size_t asrc0 = (size_t)(bm + am0) * D_ + (ak0 ^ ((am0 ^ (am0 >> 2)) & 3)) * 8;
  const size_t asrc1 = (size_t)(bm + am1) * D_ + (ak1 ^ ((am1 ^ (am1 >> 2)) & 3)) * 8;
  const size_t bsrc0 = (size_t)(bn + am0) * D_ + (ak0 ^ ((am0 ^ (am0 >> 2)) & 3)) * 8;
  const size_t bsrc1 = (size_t)(bn + am1) * D_ + (ak1 ^ ((am1 ^ (am1 >> 2)) & 3)) * 8;
  const int dst0 = (wave * 64) * 16, dst1 = (256 + wave * 64) * 16;

#define STG(kofs, bi)                                     \
  do {                                                    \
    gload16(A + asrc0 + (kofs), (char*)As[bi] + dst0);    \
    gload16(A + asrc1 + (kofs), (char*)As[bi] + dst1);    \
    gload16(Bt + bsrc0 + (kofs), (char*)Bs[bi] + dst0);   \
    gload16(Bt + bsrc1 + (kofs), (char*)Bs[bi] + dst1);   \
  } while (0)

  STG(0, 0);
  STG(32, 1);
  int cur = 0;
  for (int s = 0; s < 32; ++s) {
    WAITL();
    WAITV(4);
    BAR();
    SCHED0();
    if (s + 2 < 32) {
      int stg = cur == 0 ? 2 : cur - 1;
      STG((size_t)(s + 2) * 32, stg);
    }
    bf16x8 a[4], b[4];
#pragma unroll
    for (int mi = 0; mi < 4; ++mi) {
      int row = wr + mi * 16 + c;
      a[mi] = *(const bf16x8*)((const char*)As[cur] + row * 64 +
                               ((g ^ ((row ^ (row >> 2)) & 3)) << 4));
    }
#pragma unroll
    for (int ni = 0; ni < 4; ++ni) {
      int row = wc + ni * 16 + c;
      b[ni] = *(const bf16x8*)((const char*)Bs[cur] + row * 64 +
                               ((g ^ ((row ^ (row >> 2)) & 3)) << 4));
    }
#pragma unroll
    for (int mi = 0; mi < 4; ++mi)
#pragma unroll
      for (int ni = 0; ni < 4; ++ni)
        acc[mi][ni] =
            __builtin_amdgcn_mfma_f32_16x16x32_bf16(a[mi], b[ni], acc[mi][ni], 0, 0, 0);
    cur = cur == 2 ? 0 : cur + 1;
  }
#undef STG

  __hip_bfloat16* Chead = mat == 0 ? Qh : Kh;
#pragma unroll
  for (int mi = 0; mi < 4; ++mi) {
#pragma unroll
    for (int ni = 0; ni < 4; ++ni) {
#pragma unroll
      for (int r = 0; r < 4; ++r) {
        int grow = bm + wr + mi * 16 + g * 4 + r;
        int gcol = bn + wc + ni * 16 + c;
        float val = acc[mi][ni][r];
        int bb = grow >> 11, s = grow & 2047;
        int h = gcol >> 6, ad = gcol & 63;
        if (mat < 2)
          Chead[(((size_t)(bb * H_ + h)) * S_ + s) * AD_ + ad] = __float2bfloat16(val);
        else
          Vt[(((size_t)(bb * H_ + h)) * AD_ + ad) * S_ + s] = __float2bfloat16(val);
      }
    }
  }
}

// ---------------------------------------------------------------------------
// Fallback QKV (f32 A, VALU cast) — used if ws too small.
// ---------------------------------------------------------------------------
__global__ __launch_bounds__(256) void qkv_gemm_f32(
    const float* __restrict__ qp, const float* __restrict__ kp,
    const float* __restrict__ vp, const __hip_bfloat16* __restrict__ WtQ,
    const __hip_bfloat16* __restrict__ WtK, const __hip_bfloat16* __restrict__ WtV,
    __hip_bfloat16* __restrict__ Qh, __hip_bfloat16* __restrict__ Kh,
    __hip_bfloat16* __restrict__ Vt) {
  __shared__ alignas(16) __hip_bfloat16 As[128 * 32];
  __shared__ alignas(16) __hip_bfloat16 Bs[128 * 32];
  const int bid = blockIdx.x;
  const int xcd = bid & 7, li = bid >> 3;
  const int bmi = xcd * 4 + li / 24, ny = li % 24;
  const int mat = ny >> 3, bni = ny & 7;
  const float* A = mat == 0 ? qp : (mat == 1 ? kp : vp);
  const __hip_bfloat16* Bt = mat == 0 ? WtQ : (mat == 1 ? WtK : WtV);
  const int bm = bmi * 128, bn = bni * 128;
  const int tid = threadIdx.x;
  const int wave = tid >> 6, lane = tid & 63;
  const int g = lane >> 4, c = lane & 15;
  const int wr = (wave >> 1) * 64, wc = (wave & 1) * 64;
  f32x4 acc[4][4] = {};
  for (int k0 = 0; k0 < D_; k0 += 32) {
#pragma unroll
    for (int i = 0; i < 4; ++i) {
      int chunk = i * 256 + tid;
      int m = chunk >> 3, kc = chunk & 7;
      float4 v4 = *(const float4*)(A + (size_t)(bm + m) * D_ + k0 + kc * 4);
      ushort4 b;
      b.x = f2bf(v4.x); b.y = f2bf(v4.y); b.z = f2bf(v4.z); b.w = f2bf(v4.w);
      int sw = (kc >> 1) ^ ((m ^ (m >> 2)) & 3);
      *(ushort4*)((char*)As + m * 64 + (sw << 4) + ((kc & 1) << 3)) = b;
    }
#pragma unroll
    for (int i = 0; i < 2; ++i) {
      int cb = i * 256 + wave * 64;
      int chunk = cb + lane;
      int n = chunk >> 2, kc = chunk & 3;
      int sw = kc ^ ((n ^ (n >> 2)) & 3);
      gload16(Bt + (size_t)(bn + n) * D_ + k0 + sw * 8, (char*)Bs + cb * 16);
    }
    __syncthreads();
    bf16x8 a[4], b[4];
#pragma unroll
    for (int mi = 0; mi < 4; ++mi) {
      int row = wr + mi * 16 + c;
      a[mi] = *(const bf16x8*)((const char*)As + row * 64 +
                               ((g ^ ((row ^ (row >> 2)) & 3)) << 4));
    }
#pragma unroll
    for (int ni = 0; ni < 4; ++ni) {
      int row = wc + ni * 16 + c;
      b[ni] = *(const bf16x8*)((const char*)Bs + row * 64 +
                               ((g ^ ((row ^ (row >> 2)) & 3)) << 4));
    }
#pragma unroll
    for (int mi = 0; mi < 4; ++mi)
#pragma unroll
      for (int ni = 0; ni < 4; ++ni)
        acc[mi][ni] =
            __builtin_amdgcn_mfma_f32_16x16x32_bf16(a[mi], b[ni], acc[mi][ni], 0, 0, 0);
    __syncthreads();
  }
  __hip_bfloat16* Chead = mat == 0 ? Qh : Kh;
#pragma unroll
  for (int mi = 0; mi < 4; ++mi)
#pragma unroll
    for (int ni = 0; ni < 4; ++ni)
#pragma unroll
      for (int r = 0; r < 4; ++r) {
        int grow = bm + wr + mi * 16 + g * 4 + r;
        int gcol = bn + wc + ni * 16 + c;
        float val = acc[mi][ni][r];
        int bb = grow >> 11, s = grow & 2047;
        int h = gcol >> 6, ad = gcol & 63;
        if (mat < 2)
          Chead[(((size_t)(bb * H_ + h)) * S_ + s) * AD_ + ad] = __float2bfloat16(val);
        else
          Vt[(((size_t)(bb * H_ + h)) * AD_ + ad) * S_ + s] = __float2bfloat16(val);
      }
}

// ---------------------------------------------------------------------------
// O-projection GEMM, 128x64 tiles, 512 blocks (2/CU), XCD-chunked,
// with the qkv-verified 3-buffer depth-2 ring (counted WAITV(3) publish:
// prologue 6 in flight; at loop top oldest 3 = tile s's, drain; s+1's float).
// ---------------------------------------------------------------------------
__global__ __launch_bounds__(256) void ogemm(const __hip_bfloat16* __restrict__ A,
                                             const __hip_bfloat16* __restrict__ Bt,
                                             float* __restrict__ Cp) {
  __shared__ alignas(16) __hip_bfloat16 As[3][128 * 32];
  __shared__ alignas(16) __hip_bfloat16 Bs[3][64 * 32];
  const int bid = blockIdx.x;
  const int xcd = bid & 7, li = bid >> 3;
  const int bmi = xcd * 4 + (li >> 4), bni = li & 15;
  const int bm = bmi * 128, bn = bni * 64;
  const int tid = threadIdx.x;
  const int wave = tid >> 6, lane = tid & 63;
  const int g = lane >> 4, c = lane & 15;
  const int wr = (wave >> 1) * 64, wc = (wave & 1) * 32;
  f32x4 acc[4][2] = {};

  // staging: A 512 chunks (2/thread), B 256 chunks (1/thread); pre-swizzled src
  const int ch0 = wave * 64 + lane, ch1 = 256 + ch0;
  const int am0 = ch0 >> 2, ak0 = ch0 & 3, am1 = ch1 >> 2, ak1 = ch1 & 3;
  const size_t asrc0 = (size_t)(bm + am0) * D_ + (ak0 ^ ((am0 ^ (am0 >> 2)) & 3)) * 8;
  const size_t asrc1 = (size_t)(bm + am1) * D_ + (ak1 ^ ((am1 ^ (am1 >> 2)) & 3)) * 8;
  const size_t bsrc0 = (size_t)(bn + am0) * D_ + (ak0 ^ ((am0 ^ (am0 >> 2)) & 3)) * 8;
  const int dst0 = (wave * 64) * 16, dst1 = (256 + wave * 64) * 16;

#define OSTG(kofs, bi)                                    \
  do {                                                    \
    gload16(A + asrc0 + (kofs), (char*)As[bi] + dst0);    \
    gload16(A + asrc1 + (kofs), (char*)As[bi] + dst1);    \
    gload16(Bt + bsrc0 + (kofs), (char*)Bs[bi] + dst0);   \
  } while (0)

  OSTG(0, 0);
  OSTG(32, 1);
  int cur = 0;
  for (int s = 0; s < 32; ++s) {
    WAITL();
    WAITV(3);
    BAR();
    SCHED0();
    if (s + 2 < 32) {
      int stg = cur == 0 ? 2 : cur - 1;
      OSTG((size_t)(s + 2) * 32, stg);
    }
    bf16x8 a[4], b[2];
#pragma unroll
    for (int mi = 0; mi < 4; ++mi) {
      int row = wr + mi * 16 + c;
      a[mi] = *(const bf16x8*)((const char*)As[cur] + row * 64 +
                               ((g ^ ((row ^ (row >> 2)) & 3)) << 4));
    }
#pragma unroll
    for (int ni = 0; ni < 2; ++ni) {
      int row = wc + ni * 16 + c;
      b[ni] = *(const bf16x8*)((const char*)Bs[cur] + row * 64 +
                               ((g ^ ((row ^ (row >> 2)) & 3)) << 4));
    }
#pragma unroll
    for (int mi = 0; mi < 4; ++mi)
#pragma unroll
      for (int ni = 0; ni < 2; ++ni)
        acc[mi][ni] =
            __builtin_amdgcn_mfma_f32_16x16x32_bf16(a[mi], b[ni], acc[mi][ni], 0, 0, 0);
    cur = cur == 2 ? 0 : cur + 1;
  }
#undef OSTG

#pragma unroll
  for (int mi = 0; mi < 4; ++mi)
#pragma unroll
    for (int ni = 0; ni < 2; ++ni)
#pragma unroll
      for (int r = 0; r < 4; ++r) {
        int grow = bm + wr + mi * 16 + g * 4 + r;
        int gcol = bn + wc + ni * 16 + c;
        Cp[(size_t)grow * 1024 + gcol] = acc[mi][ni][r];
      }
}

// ---------------------------------------------------------------------------
// Fused attention v5 (byte-exact revert to the verified 282.9 µs config):
// 128 q-rows/block (8 waves), KVBLK=64, 48 KB LDS (3 blocks/CU), swapped-
// operand QK^T, dbuf staging, counted-vmcnt publish, XCD decode.
//   pass 1: stage K, QK^T + exp + rowsum (WAITV(0) — no stores in flight).
//   pass 2: stage K+V, QK^T, exp*invZ, f32x4 attn store, P-pack, PV
//           (WAITV(4): own 2 loads drained; 4 prev stores float across BAR).
// ---------------------------------------------------------------------------
__global__ __launch_bounds__(512) void attn_fused(const __hip_bfloat16* __restrict__ Qh,
                                                  const __hip_bfloat16* __restrict__ Kh,
                                                  const __hip_bfloat16* __restrict__ Vt,
                                                  float* __restrict__ attn,
                                                  __hip_bfloat16* __restrict__ ctx) {
  __shared__ alignas(16) __hip_bfloat16 Kbuf[2][64 * 64];
  __shared__ alignas(16) __hip_bfloat16 Vbuf[2][64 * 64];
  __shared__ alignas(16) __hip_bfloat16 Ps[8][16 * 64];
  const int tid = threadIdx.x;
  const int wave = tid >> 6, lane = tid & 63;
  const int g = lane >> 4, c = lane & 15;
  // 512 blocks = 8 XCDs x (4 bh x 16 qt)
  const int bid = blockIdx.x;
  const int xcd = bid & 7, li = bid >> 3;
  const int bh = xcd * 4 + (li >> 4), qt = li & 15;
  const int qrow0 = qt * 128 + wave * 16;

  const __hip_bfloat16* Kbh = Kh + (size_t)bh * S_ * AD_;
  const __hip_bfloat16* Vbh = Vt + (size_t)bh * AD_ * S_;

  const __hip_bfloat16* Qbase = Qh + ((size_t)bh * S_ + qrow0 + c) * AD_;
  bf16x8 qa0 = *(const bf16x8*)(Qbase + g * 8);
  bf16x8 qa1 = *(const bf16x8*)(Qbase + 32 + g * 8);

  // staging: 512 chunks of 16B per 64x64 tile, 512 threads -> 1 chunk each
  const int ch = wave * 64 + lane;
  const int r0 = ch >> 3, q0 = ch & 7;
  const int ksrc = r0 * AD_ + ((q0 ^ (r0 & 7)) * 8);            // K: [key][ad]
  const size_t vsrc = (size_t)r0 * S_ + ((q0 ^ (r0 & 7)) * 8);  // V: [ad][s]
  const int dstu = wave * 1024;  // wave-uniform; HW adds lane*16

#define STAGE_K(kt, bufp) \
  gload16(Kbh + (size_t)(kt) * 64 * AD_ + ksrc, (char*)(bufp) + dstu)
#define STAGE_V(kt, bufp) \
  gload16(Vbh + (size_t)(kt) * 64 + vsrc, (char*)(bufp) + dstu)

  const int csw = c & 7;

  // ---- pass 1: row sums ----
  STAGE_K(0, Kbuf[0]);
  float rowsum = 0.f;
  for (int kt = 0; kt < 32; ++kt) {
    const int cur = kt & 1;
    WAITL();
    WAITV(0);  // publish own stage of tile kt
    BAR();
    SCHED0();
    if (kt < 31) STAGE_K(kt + 1, Kbuf[cur ^ 1]);
    const char* Kc = (const char*)Kbuf[cur];
#pragma unroll
    for (int t = 0; t < 4; ++t) {
      const char* kb = Kc + (t * 16 + c) * 128;
      bf16x8 k0 = *(const bf16x8*)(kb + ((g ^ csw) << 4));
      bf16x8 k1 = *(const bf16x8*)(kb + (((4 + g) ^ csw) << 4));
      f32x4 s = {0.f, 0.f, 0.f, 0.f};
      s = __builtin_amdgcn_mfma_f32_16x16x32_bf16(k0, qa0, s, 0, 0, 0);
      s = __builtin_amdgcn_mfma_f32_16x16x32_bf16(k1, qa1, s, 0, 0, 0);
#pragma unroll
      for (int r = 0; r < 4; ++r) rowsum += __expf(s[r] * 0.125f);
    }
  }
  rowsum += __shfl_xor(rowsum, 16);
  rowsum += __shfl_xor(rowsum, 32);
  const float invZ = 1.0f / rowsum;

  // ---- pass 2: attn write + PV ----
  f32x4 ctxacc[4] = {};
  float* attn_row = attn + ((size_t)bh * S_ + qrow0 + c) * S_;
  char* Pw = (char*)Ps[wave] + c * 128;

  STAGE_K(0, Kbuf[0]);
  STAGE_V(0, Vbuf[0]);
  WAITV(0);
  for (int kt = 0; kt < 32; ++kt) {
    const int cur = kt & 1;
    WAITL();
    WAITV(4);  // own 2 staging loads of kt drained; 4 prev stores float on
    BAR();
    SCHED0();
    if (kt < 31) {
      STAGE_K(kt + 1, Kbuf[cur ^ 1]);
      STAGE_V(kt + 1, Vbuf[cur ^ 1]);
    }
    const char* Kc = (const char*)Kbuf[cur];
#pragma unroll
    for (int t = 0; t < 4; ++t) {
      const char* kb = Kc + (t * 16 + c) * 128;
      bf16x8 k0 = *(const bf16x8*)(kb + ((g ^ csw) << 4));
      bf16x8 k1 = *(const bf16x8*)(kb + (((4 + g) ^ csw) << 4));
      f32x4 s = {0.f, 0.f, 0.f, 0.f};
      s = __builtin_amdgcn_mfma_f32_16x16x32_bf16(k0, qa0, s, 0, 0, 0);
      s = __builtin_amdgcn_mfma_f32_16x16x32_bf16(k1, qa1, s, 0, 0, 0);
      f32x4 p;
#pragma unroll
      for (int r = 0; r < 4; ++r) p[r] = __expf(s[r] * 0.125f) * invZ;
      *(f32x4*)(attn_row + kt * 64 + t * 16 + g * 4) = p;
      ushort4 pk;
      pk.x = f2bf(p[0]); pk.y = f2bf(p[1]); pk.z = f2bf(p[2]); pk.w = f2bf(p[3]);
      *(ushort4*)(Pw + (((2 * t + (g >> 1)) ^ csw) << 4) + ((g & 1) << 3)) = pk;
    }
    const char* Vc = (const char*)Vbuf[cur];
#pragma unroll
    for (int h2 = 0; h2 < 2; ++h2) {
      bf16x8 pa = *(const bf16x8*)(Pw + ((((h2 << 2) + g) ^ csw) << 4));
#pragma unroll
      for (int ni = 0; ni < 4; ++ni) {
        const char* vrow = Vc + (ni * 16 + c) * 128;
        bf16x8 vb = *(const bf16x8*)(vrow + (((h2 * 4 + g) ^ csw) << 4));
        ctxacc[ni] = __builtin_amdgcn_mfma_f32_16x16x32_bf16(pa, vb, ctxacc[ni], 0, 0, 0);
      }
    }
  }
#undef STAGE_K
#undef STAGE_V

  const int b = bh >> 4, h = bh & 15;
#pragma unroll
  for (int ni = 0; ni < 4; ++ni) {
#pragma unroll
    for (int r = 0; r < 4; ++r) {
      int qg = qrow0 + g * 4 + r;
      int col = h * 64 + ni * 16 + c;
      ctx[((size_t)b * S_ + qg) * 1024 + col] = __float2bfloat16(ctxacc[ni][r]);
    }
  }
}

// ---------------------------------------------------------------------------
extern "C" void kernel_launch(void* const* d_in, const int* in_sizes, int n_in,
                              void* d_out, int out_size, void* d_ws, size_t ws_size,
                              hipStream_t stream) {
  const float* q = (const float*)d_in[0];
  const float* k = (const float*)d_in[1];
  const float* v = (const float*)d_in[2];
  const float* WQ = (const float*)d_in[3];
  const float* WK = (const float*)d_in[4];
  const float* WV = (const float*)d_in[5];
  const float* WO = (const float*)d_in[6];

  float* out_x = (float*)d_out;                      // (B,S,1024) f32
  float* out_attn = out_x + (size_t)B_ * S_ * 1024;  // (B,H,S,S)  f32

  const size_t W1 = 1048576;  // elems per Wt
  const size_t T4 = 4194304;  // elems per (B,S,D) bf16 tensor
  __hip_bfloat16* base = (__hip_bfloat16*)d_ws;
  __hip_bfloat16* WtQ = base;
  __hip_bfloat16* WtK = WtQ + W1;
  __hip_bfloat16* WtV = WtK + W1;
  __hip_bfloat16* WtO = WtV + W1;
  __hip_bfloat16* Qh = WtO + W1;
  __hip_bfloat16* Kh = Qh + T4;
  __hip_bfloat16* Vt = Kh + T4;

  wtrans4<<<dim3(16, 16, 4), 256, 0, stream>>>(WQ, WK, WV, WO, WtQ, WtK, WtV, WtO);

  if (ws_size >= (4 * W1 + 6 * T4) * sizeof(__hip_bfloat16)) {
    __hip_bfloat16* Qb = Vt + T4;
    __hip_bfloat16* Kb = Qb + T4;
    __hip_bfloat16* Vb = Kb + T4;
    __hip_bfloat16* ctx = Qb;  // Qb dead after qkv_gemm; reuse for ctx
    castbf3<<<6144, 256, 0, stream>>>(q, k, v, Qb, Kb, Vb);
    qkv_gemm<<<768, 256, 0, stream>>>(Qb, Kb, Vb, WtQ, WtK, WtV, Qh, Kh, Vt);
    attn_fused<<<512, 512, 0, stream>>>(Qh, Kh, Vt, out_attn, ctx);
    ogemm<<<512, 256, 0, stream>>>(ctx, WtO, out_x);
  } else {
    __hip_bfloat16* ctx = Vt + T4;
    qkv_gemm_f32<<<768, 256, 0, stream>>>(q, k, v, WtQ, WtK, WtV, Qh, Kh, Vt);
    attn_fused<<<512, 512, 0, stream>>>(Qh, Kh, Vt, out_attn, ctx);
    ogemm<<<512, 256, 0, stream>>>(ctx, WtO, out_x);
  }
}